// Round 9
// baseline (345.874 us; speedup 1.0000x reference)
//
#include <hip/hip_runtime.h>

typedef unsigned short u16;
typedef __bf16 bf16x8 __attribute__((ext_vector_type(8)));
typedef float f32x4 __attribute__((ext_vector_type(4)));
typedef unsigned short u16x8 __attribute__((ext_vector_type(8)));

constexpr int NN  = 10000;   // nodes
constexpr int NE  = 160000;  // edges
constexpr int NG  = 32;      // graphs
constexpr int HD  = 128;     // hidden

// ---- workspace layout (bytes) ----
constexpr size_t WT_PQ   = 0;                  // [2][512][128] bf16 (msgW1 split/transposed)
constexpr size_t WT_U1C  = 917504;             // [2][256][384] bf16 (combined UPD1' weight)
constexpr size_t WT_UPD2 = 1310720;            // [2][128][256]
constexpr size_t WT_NODE = 1441792;            // [256][128]
constexpr size_t OFF_C2  = 1507328;            // f32 [2][256]
constexpr size_t OFF_DEG = 1509376;            // int [2][NN]
constexpr size_t OFF_ST  = 1589376;            // int [2][NN+8]
constexpr size_t OFF_CUR = 1669440;            // int [2][NN]
constexpr size_t OFF_SRC = 1749440;            // int [2][NE]
constexpr size_t OFF_H   = 3029440;            // f32 [2][NN][128]
constexpr size_t OFF_HB  = 13269440;           // bf16 [2][NN][128]
constexpr size_t OFF_PQ  = 18389440;           // bf16 [2][NN][512]
constexpr size_t OFF_UI  = 38869440;           // bf16 [2][NN][384]
constexpr size_t OFF_G   = 54229440;           // f32 [2][NG][128]
constexpr size_t OFF_XB  = 54262208;           // bf16 [2][NN][64]
constexpr size_t WT_EMB  = 56822208;           // [128][64] bf16 (W_emb transposed)
constexpr size_t OFF_U1  = 56838592;           // bf16 [2][NN][256]

#define LSTR 40

__device__ inline u16 f2b(float f) {
  unsigned int u = __float_as_uint(f);
  unsigned int r = u + 0x7fffu + ((u >> 16) & 1u);
  return (u16)(r >> 16);
}
__device__ inline float b2f(u16 u) { return __uint_as_float(((unsigned int)u) << 16); }

// ---------------- weight prep (+ Wc, c2, xb cast, zero deg/g) ----------------
__global__ __launch_bounds__(256) void k_prep(
    const float* msgW1, const float* msgW2, const float* updW1,
    const float* updW2, const float* nodeW, const float* msgb2,
    const float* W_emb, const float* x1, const float* x2,
    u16* tpq, u16* tu1c, u16* t4, u16* t5, u16* temb, u16* xb,
    float* c2, int* deg, float* g) {
  int idx = blockIdx.x * 256 + threadIdx.x;
  if (idx < 131072) {
    // wt_pq: [l][n=512][k=128]; n<256 -> W1[k][n] (src half), n>=256 -> W1[128+k][n-256]
    int l = idx >> 16, r = idx & 65535, n = r >> 7, k = r & 127;
    int row = (n < 256) ? k : (128 + k);
    tpq[idx] = f2b(msgW1[l * 65536 + row * 256 + (n & 255)]);
  }
  if (idx < 65536) {   // u1c h-part: [l][n=256][256+k], k<128 <- updW1[l][256+k][n]
    int l = idx >> 15, r = idx & 32767, n = r >> 7, k = r & 127;
    tu1c[l * 98304 + n * 384 + 256 + k] = f2b(updW1[l * 98304 + (256 + k) * 256 + n]);
    // updW2: [l][k=256][n=128] -> [l][n=128][k=256]
    int n2 = (idx & 32767) >> 8, k2 = idx & 255;
    t4[idx] = f2b(updW2[(idx >> 15) * 32768 + (k2 << 7) + n2]);
  }
  if (idx < 32768) {   // nodeW: [k=128][n=256] -> [n=256][k=128]
    int n = idx >> 7, k = idx & 127;
    t5[idx] = f2b(nodeW[(k << 8) + n]);
  }
  if (idx < 512) {     // c2[l][n] = sum_c msg_b2[l][c] * updW1[l][c][n]
    int l = idx >> 8, n = idx & 255;
    const float* b2 = msgb2 + l * 256;
    const float* U1 = updW1 + l * 98304 + n;
    float a = 0.f;
    for (int c = 0; c < 256; c++) a += b2[c] * U1[c * 256];
    c2[idx] = a;
  }
  if (idx < 2 * NN) deg[idx] = 0;
  if (idx < 2 * NG * 128) g[idx] = 0.f;
  if (idx >= 131072 && idx < 262144) {
    // Wc = W2 @ W1u_top (fp32 accumulate): tu1c[l][n][k<256] = sum_c W2[k][c]*W1u[c][n]
    int j = idx - 131072;
    int l = j >> 16, r = j & 65535, k = r >> 8, n = r & 255;
    const float* w2p = msgW2 + l * 65536 + k * 256;
    const float* u1p = updW1 + l * 98304 + n;
    float a = 0.f;
    for (int c = 0; c < 256; c++) a += w2p[c] * u1p[c * 256];
    tu1c[l * 98304 + n * 384 + k] = f2b(a);
  }
  if (idx >= 262144 && idx < 270336) {
    // wt_emb: [n=128][k=64] <- W_emb[k][n]
    int j = idx - 262144;
    int n = j >> 6, k = j & 63;
    temb[j] = f2b(W_emb[(k << 7) + n]);
  }
  if (idx >= 270336 && idx < 1550336) {
    // xb cast: [2][NN][64] bf16
    int j = idx - 270336;
    int br = j >= NN * 64;
    int jj = br ? j - NN * 64 : j;
    const float* x = br ? x2 : x1;
    xb[(size_t)br * NN * 64 + jj] = f2b(x[jj]);
  }
}

// ---------------- counting sort of edges by tgt ----------------
__global__ __launch_bounds__(256) void k_deg(const int* ei0, const int* ei1, int* deg) {
  int br = blockIdx.z;
  int e = blockIdx.x * 256 + threadIdx.x;
  if (e >= NE) return;
  const int* tgt = br ? ei1 : ei0;
  atomicAdd(deg + br * NN + tgt[e], 1);
}

__global__ __launch_bounds__(256) void k_scan(const int* deg, int* starts, int* cursor) {
  int br = blockIdx.z;
  const int* d = deg + br * NN;
  int* st = starts + br * (NN + 8);
  int* cu = cursor + br * NN;
  __shared__ int part[257];
  int t = threadIdx.x;
  int c0 = t * 40;
  int s = 0;
  for (int i = 0; i < 40; i++) if (c0 + i < NN) s += d[c0 + i];
  part[t] = s;
  __syncthreads();
  if (t == 0) {
    int run = 0;
    for (int i = 0; i < 256; i++) { int v = part[i]; part[i] = run; run += v; }
    part[256] = run;
  }
  __syncthreads();
  int run = part[t];
  for (int i = 0; i < 40; i++) {
    int n = c0 + i;
    if (n < NN) { st[n] = run; cu[n] = run; run += d[n]; }
  }
  if (t == 255) st[NN] = part[256];
}

__global__ __launch_bounds__(256) void k_scatter(const int* ei0, const int* ei1,
                                                 int* cursor, int* srcs) {
  int br = blockIdx.z;
  int e = blockIdx.x * 256 + threadIdx.x;
  if (e >= NE) return;
  const int* ei = br ? ei1 : ei0;
  int t = ei[e], s = ei[NE + e];
  int pos = atomicAdd(cursor + br * NN + t, 1);
  srcs[br * NE + pos] = s;
}

// ---------------- shared phase: PQ strip from lhb (32x128 bf16, stride 136) -------
__device__ __forceinline__ void pq_from_lhb(
    const u16* lhb, const u16* wq, u16* PQ, int m0, int wave, int lane) {
  const int q = lane >> 4, lr = lane & 15;
  f32x4 a3[2][8];
#pragma unroll
  for (int i = 0; i < 2; i++)
#pragma unroll
    for (int j = 0; j < 8; j++) a3[i][j] = (f32x4){0.f, 0.f, 0.f, 0.f};
#pragma unroll
  for (int k0 = 0; k0 < 128; k0 += 32) {
    bf16x8 af[2], bfr[8];
#pragma unroll
    for (int i = 0; i < 2; i++)
      af[i] = *(const bf16x8*)&lhb[(i * 16 + lr) * 136 + k0 + q * 8];
#pragma unroll
    for (int i = 0; i < 8; i++)
      bfr[i] = *(const bf16x8*)(wq + (size_t)(wave * 128 + i * 16 + lr) * 128 + k0 + q * 8);
#pragma unroll
    for (int mi = 0; mi < 2; mi++)
#pragma unroll
      for (int ni = 0; ni < 8; ni++)
        a3[mi][ni] = __builtin_amdgcn_mfma_f32_16x16x32_bf16(af[mi], bfr[ni], a3[mi][ni], 0, 0, 0);
  }
#pragma unroll
  for (int mi = 0; mi < 2; mi++)
#pragma unroll
    for (int rg = 0; rg < 4; rg++) {
      int grow = m0 + mi * 16 + q * 4 + rg;
      if (grow >= NN) continue;
#pragma unroll
      for (int ni = 0; ni < 8; ni++) {
        int col = wave * 128 + ni * 16 + lr;
        PQ[(size_t)grow * 512 + col] = f2b(a3[mi][ni][rg]);
      }
    }
}

// ---------------- embedding via MFMA: h = xb @ W_emb^T + b; + PQ(l=0) ------------
__global__ __launch_bounds__(256) void k_embed(
    const u16* xb_all, const u16* wemb, const float* b,
    float* h, u16* h_bf, u16* ui, const u16* wpq0, u16* PQ_all) {
  const int br = blockIdx.z;
  const int tid = threadIdx.x;
  const int lane = tid & 63, wave = tid >> 6;
  const int q = lane >> 4, lr = lane & 15;
  const int m0 = blockIdx.x * 32;

  __shared__ alignas(16) u16 lx[32 * 72];
  __shared__ alignas(16) u16 lhb[32 * 136];

  const u16* xb = xb_all + (size_t)br * NN * 64;
  {
    int r = tid >> 3, kc = (tid & 7) * 8;
    int gr = m0 + r;
    u16x8 v = {0, 0, 0, 0, 0, 0, 0, 0};
    if (gr < NN) v = *(const u16x8*)(xb + (size_t)gr * 64 + kc);
    *(u16x8*)&lx[r * 72 + kc] = v;
  }
  __syncthreads();

  const int wn = wave * 32;
  f32x4 acc[2][2];
#pragma unroll
  for (int i = 0; i < 2; i++)
#pragma unroll
    for (int j = 0; j < 2; j++) acc[i][j] = (f32x4){0.f, 0.f, 0.f, 0.f};

#pragma unroll
  for (int k0 = 0; k0 < 64; k0 += 32) {
    bf16x8 af[2], bfr[2];
#pragma unroll
    for (int i = 0; i < 2; i++)
      af[i] = *(const bf16x8*)&lx[(i * 16 + lr) * 72 + k0 + q * 8];
#pragma unroll
    for (int i = 0; i < 2; i++)
      bfr[i] = *(const bf16x8*)(wemb + (size_t)(wn + i * 16 + lr) * 64 + k0 + q * 8);
#pragma unroll
    for (int mi = 0; mi < 2; mi++)
#pragma unroll
      for (int ni = 0; ni < 2; ni++)
        acc[mi][ni] = __builtin_amdgcn_mfma_f32_16x16x32_bf16(af[mi], bfr[ni], acc[mi][ni], 0, 0, 0);
  }

  float* hB = h + (size_t)br * NN * HD;
  u16* hbB = h_bf + (size_t)br * NN * HD;
  u16* uiB = ui + (size_t)br * NN * 384;
#pragma unroll
  for (int mi = 0; mi < 2; mi++)
#pragma unroll
    for (int rg = 0; rg < 4; rg++) {
      int lrow = mi * 16 + q * 4 + rg;
      int gr = m0 + lrow;
#pragma unroll
      for (int ni = 0; ni < 2; ni++) {
        int col = wn + ni * 16 + lr;
        if (gr < NN) {
          float nh = acc[mi][ni][rg] + b[col];
          u16 bv = f2b(nh);
          hB[(size_t)gr * HD + col] = nh;
          hbB[(size_t)gr * HD + col] = bv;
          uiB[(size_t)gr * 384 + 256 + col] = bv;
          lhb[lrow * 136 + col] = bv;
        } else {
          lhb[lrow * 136 + col] = 0;
        }
      }
    }
  __syncthreads();
  pq_from_lhb(lhb, wpq0, PQ_all + (size_t)br * NN * 512, m0, wave, lane);
}

// ---------------- edge phase: ui[n][:256] = sum_e relu(P[src_e] + Q[n] + b1) ------
__global__ __launch_bounds__(256) void k_edge(const u16* PQ, const int* starts,
                                              const int* srcs, const float* b1, u16* ui) {
  int br = blockIdx.z;
  int node = blockIdx.x * 4 + (threadIdx.x >> 6);
  int lane = threadIdx.x & 63;
  int half = lane >> 5;
  int c0 = (lane & 31) * 8;
  const u16* PQb = PQ + (size_t)br * NN * 512;
  const int* st = starts + br * (NN + 8);
  const int* sr = srcs + br * NE;
  u16x8 qr = *(const u16x8*)(PQb + (size_t)node * 512 + 256 + c0);
  float qv[8], acc[8];
#pragma unroll
  for (int j = 0; j < 8; j++) { qv[j] = b2f(qr[j]) + b1[c0 + j]; acc[j] = 0.f; }
  int e0 = st[node], e1 = st[node + 1];
  int mid = e0 + ((e1 - e0 + 1) >> 1);
  int e = half ? mid : e0;
  int ee = half ? e1 : mid;
  for (; e + 3 < ee; e += 4) {
    int s0 = sr[e], s1 = sr[e + 1], s2 = sr[e + 2], s3 = sr[e + 3];
    u16x8 p0 = *(const u16x8*)(PQb + (size_t)s0 * 512 + c0);
    u16x8 p1 = *(const u16x8*)(PQb + (size_t)s1 * 512 + c0);
    u16x8 p2 = *(const u16x8*)(PQb + (size_t)s2 * 512 + c0);
    u16x8 p3 = *(const u16x8*)(PQb + (size_t)s3 * 512 + c0);
#pragma unroll
    for (int j = 0; j < 8; j++) {
      float v0 = b2f(p0[j]) + qv[j];
      float v1 = b2f(p1[j]) + qv[j];
      float v2 = b2f(p2[j]) + qv[j];
      float v3 = b2f(p3[j]) + qv[j];
      acc[j] += (v0 > 0.f ? v0 : 0.f) + (v1 > 0.f ? v1 : 0.f)
              + (v2 > 0.f ? v2 : 0.f) + (v3 > 0.f ? v3 : 0.f);
    }
  }
  for (; e + 1 < ee; e += 2) {
    int s0 = sr[e], s1 = sr[e + 1];
    u16x8 p0 = *(const u16x8*)(PQb + (size_t)s0 * 512 + c0);
    u16x8 p1 = *(const u16x8*)(PQb + (size_t)s1 * 512 + c0);
#pragma unroll
    for (int j = 0; j < 8; j++) {
      float v0 = b2f(p0[j]) + qv[j];
      float v1 = b2f(p1[j]) + qv[j];
      acc[j] += (v0 > 0.f ? v0 : 0.f) + (v1 > 0.f ? v1 : 0.f);
    }
  }
  if (e < ee) {
    int s0 = sr[e];
    u16x8 p0 = *(const u16x8*)(PQb + (size_t)s0 * 512 + c0);
#pragma unroll
    for (int j = 0; j < 8; j++) {
      float v0 = b2f(p0[j]) + qv[j];
      acc[j] += (v0 > 0.f ? v0 : 0.f);
    }
  }
#pragma unroll
  for (int j = 0; j < 8; j++) acc[j] += __shfl_xor(acc[j], 32);
  if (half == 0) {
    u16x8 o;
#pragma unroll
    for (int j = 0; j < 8; j++) o[j] = f2b(acc[j]);
    *(u16x8*)(ui + (size_t)br * NN * 384 + (size_t)node * 384 + c0) = o;
  }
}

// ---------------- UPD1': 128x128-tile GEMM, U1 = relu(ui@W1c + b1u + deg*c2) ------
__global__ __launch_bounds__(256) void k_upd1(
    const u16* ui_all, const u16* w1c, const float* b1u, const float* c2l,
    const int* deg_all, u16* U1_all) {
  const int br = blockIdx.z;
  const int tid = threadIdx.x;
  const int lane = tid & 63, wave = tid >> 6;
  const int wm = (wave & 1) * 64, wn = (wave >> 1) * 64;
  const int q = lane >> 4, lr = lane & 15;
  const int m0 = blockIdx.x * 128, n0 = blockIdx.y * 128;
  __shared__ alignas(16) u16 lA[128 * LSTR];
  __shared__ alignas(16) u16 lB[128 * LSTR];

  f32x4 acc[4][4];
#pragma unroll
  for (int i = 0; i < 4; i++)
#pragma unroll
    for (int j = 0; j < 4; j++) acc[i][j] = (f32x4){0.f, 0.f, 0.f, 0.f};

  const u16* ui = ui_all + (size_t)br * NN * 384;

  for (int k0 = 0; k0 < 384; k0 += 32) {
#pragma unroll
    for (int c = tid; c < 512; c += 256) {
      int r = c >> 2, kc = (c & 3) << 3;
      int gr = m0 + r;
      u16x8 v = {0, 0, 0, 0, 0, 0, 0, 0};
      if (gr < NN) v = *(const u16x8*)(ui + (size_t)gr * 384 + k0 + kc);
      *(u16x8*)&lA[r * LSTR + kc] = v;
    }
#pragma unroll
    for (int c = tid; c < 512; c += 256) {
      int r = c >> 2, kc = (c & 3) << 3;
      *(u16x8*)&lB[r * LSTR + kc] = *(const u16x8*)(w1c + (size_t)(n0 + r) * 384 + k0 + kc);
    }
    __syncthreads();
    bf16x8 af[4], bfr[4];
#pragma unroll
    for (int i = 0; i < 4; i++) af[i] = *(const bf16x8*)&lA[(wm + i * 16 + lr) * LSTR + q * 8];
#pragma unroll
    for (int i = 0; i < 4; i++) bfr[i] = *(const bf16x8*)&lB[(wn + i * 16 + lr) * LSTR + q * 8];
#pragma unroll
    for (int mi = 0; mi < 4; mi++)
#pragma unroll
      for (int ni = 0; ni < 4; ni++)
        acc[mi][ni] = __builtin_amdgcn_mfma_f32_16x16x32_bf16(af[mi], bfr[ni], acc[mi][ni], 0, 0, 0);
    __syncthreads();
  }

  const int* deg = deg_all + br * NN;
  u16* U1 = U1_all + (size_t)br * NN * 256;
#pragma unroll
  for (int mi = 0; mi < 4; mi++)
#pragma unroll
    for (int rg = 0; rg < 4; rg++) {
      int row = m0 + wm + mi * 16 + q * 4 + rg;
      if (row >= NN) continue;
      float d = (float)deg[row];
#pragma unroll
      for (int ni = 0; ni < 4; ni++) {
        int col = n0 + wn + ni * 16 + lr;
        float v = acc[mi][ni][rg] + b1u[col] + d * c2l[col];
        if (v < 0.f) v = 0.f;
        U1[(size_t)row * 256 + col] = f2b(v);
      }
    }
}

// ---------------- UPD2 + residual + phase3 (PQ-next / readout), M-tile 64 ---------
__global__ __launch_bounds__(256, 3) void k_upd2(
    const u16* U1_all, const u16* w2, const float* b2u,
    float* h_all, u16* hb_all, u16* ui_all, int mode,
    const u16* wpq_next, u16* PQ_all,
    const u16* wnode, const float* nb, const int* b0v, const int* b1v, float* g) {
  const int br = blockIdx.z;
  const int tid = threadIdx.x;
  const int lane = tid & 63, wave = tid >> 6;
  const int q = lane >> 4, lr = lane & 15;
  const int m0 = blockIdx.x * 64;

  __shared__ alignas(16) u16 lU[64 * 264];
  __shared__ alignas(16) u16 lhb[64 * 136];
  __shared__ int sbat[64];

  const u16* U1 = U1_all + (size_t)br * NN * 256;
  // stage U1 strip [64][256]
  for (int c = tid; c < 2048; c += 256) {
    int r = c >> 5, kc = (c & 31) * 8;
    int gr = m0 + r;
    u16x8 v = {0, 0, 0, 0, 0, 0, 0, 0};
    if (gr < NN) v = *(const u16x8*)(U1 + (size_t)gr * 256 + kc);
    *(u16x8*)&lU[r * 264 + kc] = v;
  }
  if (mode == 1 && tid < 64) {
    const int* batch = br ? b1v : b0v;
    int n = m0 + tid;
    sbat[tid] = (n < NN) ? batch[n] : -1;
  }
  __syncthreads();

  // ---- phase A: h += lU @ W2^T + b2, B double-buffered from global w2 ----
  const int wn2 = wave * 32;
  f32x4 acc2[4][2];
#pragma unroll
  for (int i = 0; i < 4; i++)
#pragma unroll
    for (int j = 0; j < 2; j++) acc2[i][j] = (f32x4){0.f, 0.f, 0.f, 0.f};

  bf16x8 b2c[2], b2n[2];
#pragma unroll
  for (int i = 0; i < 2; i++)
    b2c[i] = *(const bf16x8*)(w2 + (size_t)(wn2 + i * 16 + lr) * 256 + q * 8);
#pragma unroll
  for (int k0 = 0; k0 < 256; k0 += 32) {
    if (k0 + 32 < 256) {
#pragma unroll
      for (int i = 0; i < 2; i++)
        b2n[i] = *(const bf16x8*)(w2 + (size_t)(wn2 + i * 16 + lr) * 256 + k0 + 32 + q * 8);
    }
    bf16x8 af[4];
#pragma unroll
    for (int i = 0; i < 4; i++)
      af[i] = *(const bf16x8*)&lU[(i * 16 + lr) * 264 + k0 + q * 8];
#pragma unroll
    for (int mi = 0; mi < 4; mi++)
#pragma unroll
      for (int ni = 0; ni < 2; ni++)
        acc2[mi][ni] = __builtin_amdgcn_mfma_f32_16x16x32_bf16(af[mi], b2c[ni], acc2[mi][ni], 0, 0, 0);
#pragma unroll
    for (int i = 0; i < 2; i++) b2c[i] = b2n[i];
  }

  // residual epilogue (+ stage bf16 h into lhb)
  float* h = h_all + (size_t)br * NN * 128;
  u16* hb = hb_all + (size_t)br * NN * 128;
  u16* uiw = ui_all + (size_t)br * NN * 384;
#pragma unroll
  for (int mi = 0; mi < 4; mi++)
#pragma unroll
    for (int rg = 0; rg < 4; rg++) {
      int lrow = mi * 16 + q * 4 + rg;
      int grow = m0 + lrow;
#pragma unroll
      for (int ni = 0; ni < 2; ni++) {
        int col = wn2 + ni * 16 + lr;
        if (grow < NN) {
          size_t o = (size_t)grow * 128 + col;
          float nh = h[o] + acc2[mi][ni][rg] + b2u[col];
          u16 bv = f2b(nh);
          h[o] = nh;
          hb[o] = bv;
          if (mode == 0) uiw[(size_t)grow * 384 + 256 + col] = bv;
          lhb[lrow * 136 + col] = bv;
        } else {
          lhb[lrow * 136 + col] = 0;
        }
      }
    }
  __syncthreads();

  // ---- phase B ----
  if (mode == 0) {
    // PQ(next): 64 rows x 512 cols, two N-passes of 128-col wave tiles
    u16* PQ = PQ_all + (size_t)br * NN * 512;
#pragma unroll
    for (int nh = 0; nh < 2; nh++) {
      f32x4 a3[4][4];
#pragma unroll
      for (int i = 0; i < 4; i++)
#pragma unroll
        for (int j = 0; j < 4; j++) a3[i][j] = (f32x4){0.f, 0.f, 0.f, 0.f};
#pragma unroll
      for (int k0 = 0; k0 < 128; k0 += 32) {
        bf16x8 af[4], bfr[4];
#pragma unroll
        for (int i = 0; i < 4; i++)
          af[i] = *(const bf16x8*)&lhb[(i * 16 + lr) * 136 + k0 + q * 8];
#pragma unroll
        for (int i = 0; i < 4; i++)
          bfr[i] = *(const bf16x8*)(wpq_next +
              (size_t)(wave * 128 + nh * 64 + i * 16 + lr) * 128 + k0 + q * 8);
#pragma unroll
        for (int mi = 0; mi < 4; mi++)
#pragma unroll
          for (int ni = 0; ni < 4; ni++)
            a3[mi][ni] = __builtin_amdgcn_mfma_f32_16x16x32_bf16(af[mi], bfr[ni], a3[mi][ni], 0, 0, 0);
      }
#pragma unroll
      for (int mi = 0; mi < 4; mi++)
#pragma unroll
        for (int rg = 0; rg < 4; rg++) {
          int grow = m0 + mi * 16 + q * 4 + rg;
          if (grow >= NN) continue;
#pragma unroll
          for (int ni = 0; ni < 4; ni++) {
            int col = wave * 128 + nh * 64 + ni * 16 + lr;
            PQ[(size_t)grow * 512 + col] = f2b(a3[mi][ni][rg]);
          }
        }
    }
  } else {
    // readout: 64 rows x (32 gate + 32 val) per wave
    const int wg = wave * 32;
    f32x4 a3[4][4];  // ni 0-1 gate, 2-3 val
#pragma unroll
    for (int i = 0; i < 4; i++)
#pragma unroll
      for (int j = 0; j < 4; j++) a3[i][j] = (f32x4){0.f, 0.f, 0.f, 0.f};
#pragma unroll
    for (int k0 = 0; k0 < 128; k0 += 32) {
      bf16x8 af[4], bfr[4];
#pragma unroll
      for (int i = 0; i < 4; i++)
        af[i] = *(const bf16x8*)&lhb[(i * 16 + lr) * 136 + k0 + q * 8];
#pragma unroll
      for (int i = 0; i < 4; i++) {
        int nrow = (i < 2) ? (wg + i * 16 + lr) : (128 + wg + (i - 2) * 16 + lr);
        bfr[i] = *(const bf16x8*)(wnode + (size_t)nrow * 128 + k0 + q * 8);
      }
#pragma unroll
      for (int mi = 0; mi < 4; mi++)
#pragma unroll
        for (int ni = 0; ni < 4; ni++)
          a3[mi][ni] = __builtin_amdgcn_mfma_f32_16x16x32_bf16(af[mi], bfr[ni], a3[mi][ni], 0, 0, 0);
    }
    float* gb = g + (size_t)br * NG * 128;
    float racc[2] = {0.f, 0.f};
    int cur = -1;
#pragma unroll
    for (int mi = 0; mi < 4; mi++)
#pragma unroll
      for (int rg = 0; rg < 4; rg++) {
        int lrow = mi * 16 + q * 4 + rg;
        int bt = sbat[lrow];
        if (bt != cur) {
          if (cur >= 0) {
#pragma unroll
            for (int ni = 0; ni < 2; ni++)
              atomicAdd(gb + (size_t)cur * 128 + wg + ni * 16 + lr, racc[ni]);
          }
          cur = bt;
          racc[0] = 0.f; racc[1] = 0.f;
        }
        if (bt >= 0) {
#pragma unroll
          for (int ni = 0; ni < 2; ni++) {
            int gcol = wg + ni * 16 + lr;
            float gt = a3[mi][ni][rg] + nb[gcol];
            float vl = a3[mi][ni + 2][rg] + nb[128 + gcol];
            racc[ni] += vl / (1.f + __expf(-gt));
          }
        }
      }
    if (cur >= 0) {
#pragma unroll
      for (int ni = 0; ni < 2; ni++)
        atomicAdd(gb + (size_t)cur * 128 + wg + ni * 16 + lr, racc[ni]);
    }
  }
}

// ---------------- final graph GEMM ----------------
__global__ __launch_bounds__(128) void k_final(const float* g, const float* W,
                                               const float* b, float* out) {
  int br = blockIdx.z, gi = blockIdx.x, j = threadIdx.x;
  __shared__ float sg[128];
  sg[j] = g[(size_t)br * NG * 128 + (size_t)gi * 128 + j];
  __syncthreads();
  float acc = b[j];
#pragma unroll
  for (int k = 0; k < 128; k++) acc += sg[k] * W[k * 128 + j];
  out[(size_t)br * NG * 128 + (size_t)gi * 128 + j] = acc;
}

extern "C" void kernel_launch(void* const* d_in, const int* in_sizes, int n_in,
                              void* d_out, int out_size, void* d_ws, size_t ws_size,
                              hipStream_t stream) {
  const float* x1     = (const float*)d_in[0];
  const int*   ei1    = (const int*)d_in[1];
  const int*   bat1   = (const int*)d_in[2];
  const float* x2     = (const float*)d_in[3];
  const int*   ei2    = (const int*)d_in[4];
  const int*   bat2   = (const int*)d_in[5];
  const float* W_emb  = (const float*)d_in[6];
  const float* b_emb  = (const float*)d_in[7];
  const float* msg_W1 = (const float*)d_in[8];
  const float* msg_b1 = (const float*)d_in[9];
  const float* msg_W2 = (const float*)d_in[10];
  const float* msg_b2 = (const float*)d_in[11];
  const float* upd_W1 = (const float*)d_in[12];
  const float* upd_b1 = (const float*)d_in[13];
  const float* upd_W2 = (const float*)d_in[14];
  const float* upd_b2 = (const float*)d_in[15];
  const float* node_W = (const float*)d_in[16];
  const float* node_b = (const float*)d_in[17];
  const float* graph_W = (const float*)d_in[18];
  const float* graph_b = (const float*)d_in[19];
  float* out = (float*)d_out;

  char* ws = (char*)d_ws;
  u16* wt_pq   = (u16*)(ws + WT_PQ);
  u16* wt_u1c  = (u16*)(ws + WT_U1C);
  u16* wt_upd2 = (u16*)(ws + WT_UPD2);
  u16* wt_node = (u16*)(ws + WT_NODE);
  u16* wt_emb  = (u16*)(ws + WT_EMB);
  u16* xb      = (u16*)(ws + OFF_XB);
  float* c2    = (float*)(ws + OFF_C2);
  int* deg    = (int*)(ws + OFF_DEG);
  int* starts = (int*)(ws + OFF_ST);
  int* cursor = (int*)(ws + OFF_CUR);
  int* srcs   = (int*)(ws + OFF_SRC);
  float* h  = (float*)(ws + OFF_H);
  u16*   hb = (u16*)(ws + OFF_HB);
  u16*   PQ = (u16*)(ws + OFF_PQ);
  u16*   ui = (u16*)(ws + OFF_UI);
  u16*   U1 = (u16*)(ws + OFF_U1);
  float* g  = (float*)(ws + OFF_G);

  // ---- prep (weights + Wc + c2 + xb + zero deg/g) ----
  k_prep<<<6057, 256, 0, stream>>>(msg_W1, msg_W2, upd_W1, upd_W2, node_W, msg_b2,
                                   W_emb, x1, x2,
                                   wt_pq, wt_u1c, wt_upd2, wt_node, wt_emb, xb,
                                   c2, deg, g);
  k_deg<<<dim3(625, 1, 2), 256, 0, stream>>>(ei1, ei2, deg);
  k_scan<<<dim3(1, 1, 2), 256, 0, stream>>>(deg, starts, cursor);
  k_scatter<<<dim3(625, 1, 2), 256, 0, stream>>>(ei1, ei2, cursor, srcs);
  // embed (MFMA) + PQ(l=0)
  k_embed<<<dim3(313, 1, 2), 256, 0, stream>>>(xb, wt_emb, b_emb, h, hb, ui,
                                               wt_pq, PQ);

  for (int l = 0; l < 2; l++) {
    // ui[:, :256] = S[n] = sum_{e: tgt=n} relu(P[src_e] + Q[n] + b1)
    k_edge<<<dim3(2500, 1, 2), 256, 0, stream>>>(PQ, starts, srcs, msg_b1 + l * 256, ui);

    // U1 = relu([S|h] @ W1c + b1u + deg*c2)  -- 128-tile GEMM
    k_upd1<<<dim3(79, 2, 2), 256, 0, stream>>>(
        ui, wt_u1c + (size_t)l * 98304, upd_b1 + l * 256, c2 + l * 256, deg, U1);

    // h += U1 @ W2^T + b2; then PQ(l+1) or readout
    k_upd2<<<dim3(157, 1, 2), 256, 0, stream>>>(
        U1, wt_upd2 + (size_t)l * 32768, upd_b2 + l * 128, h, hb, ui,
        (l == 0) ? 0 : 1,
        wt_pq + 65536, PQ,
        wt_node, node_b, bat1, bat2, g);
  }

  k_final<<<dim3(NG, 1, 2), 128, 0, stream>>>(g, graph_W, graph_b, out);
}

// Round 10
// 331.935 us; speedup vs baseline: 1.0420x; 1.0420x over previous
//
#include <hip/hip_runtime.h>

typedef unsigned short u16;
typedef __bf16 bf16x8 __attribute__((ext_vector_type(8)));
typedef float f32x4 __attribute__((ext_vector_type(4)));
typedef unsigned short u16x8 __attribute__((ext_vector_type(8)));

constexpr int NN  = 10000;   // nodes
constexpr int NE  = 160000;  // edges
constexpr int NG  = 32;      // graphs
constexpr int HD  = 128;     // hidden

// ---- workspace layout (bytes, 16B-aligned) ----
constexpr size_t WT_PQ   = 0;         // [2][512][128] bf16
constexpr size_t WT_U1C  = 262144;    // [2][256][384] bf16 (combined UPD1' weight)
constexpr size_t WT_UPD2 = 655360;    // [2][128][256] bf16
constexpr size_t WT_NODE = 786432;    // [256][128] bf16
constexpr size_t WT_EMB  = 851968;    // [128][64] bf16
constexpr size_t OFF_C2  = 868352;    // f32 [2][256]
constexpr size_t OFF_DEG = 870400;    // int [2][NN]
constexpr size_t OFF_ST  = 950400;    // int [2][NN+8]
constexpr size_t OFF_CUR = 1030464;   // int [2][NN]
constexpr size_t OFF_SRC = 1110464;   // int [2][NE]
constexpr size_t OFF_HB  = 2390464;   // bf16 [2][NN][128]  (h, bf16 residual state)
constexpr size_t OFF_PQ  = 7510464;   // bf16 [2][NN][512]
constexpr size_t OFF_S   = 27990464;  // bf16 [2][NN][256]
constexpr size_t OFF_G   = 38230464;  // f32 [2][NG][128]
constexpr size_t OFF_XB  = 38263232;  // bf16 [2][NN][64]

#define LSTR 40

__device__ inline u16 f2b(float f) {
  unsigned int u = __float_as_uint(f);
  unsigned int r = u + 0x7fffu + ((u >> 16) & 1u);
  return (u16)(r >> 16);
}
__device__ inline float b2f(u16 u) { return __uint_as_float(((unsigned int)u) << 16); }

// ---------------- weight prep (+ Wc, c2, xb cast, zero deg/g) ----------------
__global__ __launch_bounds__(256) void k_prep(
    const float* msgW1, const float* msgW2, const float* updW1,
    const float* updW2, const float* nodeW, const float* msgb2,
    const float* W_emb, const float* x1, const float* x2,
    u16* tpq, u16* tu1c, u16* t4, u16* t5, u16* temb, u16* xb,
    float* c2, int* deg, float* g) {
  int idx = blockIdx.x * 256 + threadIdx.x;
  if (idx < 131072) {
    // wt_pq: [l][n=512][k=128]; n<256 -> W1[k][n] (src half), n>=256 -> W1[128+k][n-256]
    int l = idx >> 16, r = idx & 65535, n = r >> 7, k = r & 127;
    int row = (n < 256) ? k : (128 + k);
    tpq[idx] = f2b(msgW1[l * 65536 + row * 256 + (n & 255)]);
  }
  if (idx < 65536) {   // u1c h-part: [l][n=256][256+k], k<128 <- updW1[l][256+k][n]
    int l = idx >> 15, r = idx & 32767, n = r >> 7, k = r & 127;
    tu1c[l * 98304 + n * 384 + 256 + k] = f2b(updW1[l * 98304 + (256 + k) * 256 + n]);
    // updW2: [l][k=256][n=128] -> [l][n=128][k=256]
    int n2 = (idx & 32767) >> 8, k2 = idx & 255;
    t4[idx] = f2b(updW2[(idx >> 15) * 32768 + (k2 << 7) + n2]);
  }
  if (idx < 32768) {   // nodeW: [k=128][n=256] -> [n=256][k=128]
    int n = idx >> 7, k = idx & 127;
    t5[idx] = f2b(nodeW[(k << 8) + n]);
  }
  if (idx < 512) {     // c2[l][n] = sum_c msg_b2[l][c] * updW1[l][c][n]
    int l = idx >> 8, n = idx & 255;
    const float* b2 = msgb2 + l * 256;
    const float* U1 = updW1 + l * 98304 + n;
    float a = 0.f;
    for (int c = 0; c < 256; c++) a += b2[c] * U1[c * 256];
    c2[idx] = a;
  }
  if (idx < 2 * NN) deg[idx] = 0;
  if (idx < 2 * NG * 128) g[idx] = 0.f;
  if (idx >= 131072 && idx < 262144) {
    // Wc = W2 @ W1u_top (fp32 accumulate): tu1c[l][n][k<256] = sum_c W2[k][c]*W1u[c][n]
    int j = idx - 131072;
    int l = j >> 16, r = j & 65535, k = r >> 8, n = r & 255;
    const float* w2p = msgW2 + l * 65536 + k * 256;
    const float* u1p = updW1 + l * 98304 + n;
    float a = 0.f;
    for (int c = 0; c < 256; c++) a += w2p[c] * u1p[c * 256];
    tu1c[l * 98304 + n * 384 + k] = f2b(a);
  }
  if (idx >= 262144 && idx < 270336) {
    // wt_emb: [n=128][k=64] <- W_emb[k][n]
    int j = idx - 262144;
    int n = j >> 6, k = j & 63;
    temb[j] = f2b(W_emb[(k << 7) + n]);
  }
  if (idx >= 270336 && idx < 1550336) {
    // xb cast: [2][NN][64] bf16
    int j = idx - 270336;
    int br = j >= NN * 64;
    int jj = br ? j - NN * 64 : j;
    const float* x = br ? x2 : x1;
    xb[(size_t)br * NN * 64 + jj] = f2b(x[jj]);
  }
}

// ---------------- counting sort of edges by tgt ----------------
__global__ __launch_bounds__(256) void k_deg(const int* ei0, const int* ei1, int* deg) {
  int br = blockIdx.z;
  int e = blockIdx.x * 256 + threadIdx.x;
  if (e >= NE) return;
  const int* tgt = br ? ei1 : ei0;
  atomicAdd(deg + br * NN + tgt[e], 1);
}

__global__ __launch_bounds__(256) void k_scan(const int* deg, int* starts, int* cursor) {
  int br = blockIdx.z;
  const int* d = deg + br * NN;
  int* st = starts + br * (NN + 8);
  int* cu = cursor + br * NN;
  __shared__ int part[257];
  int t = threadIdx.x;
  int c0 = t * 40;
  int s = 0;
  for (int i = 0; i < 40; i++) if (c0 + i < NN) s += d[c0 + i];
  part[t] = s;
  __syncthreads();
  if (t == 0) {
    int run = 0;
    for (int i = 0; i < 256; i++) { int v = part[i]; part[i] = run; run += v; }
    part[256] = run;
  }
  __syncthreads();
  int run = part[t];
  for (int i = 0; i < 40; i++) {
    int n = c0 + i;
    if (n < NN) { st[n] = run; cu[n] = run; run += d[n]; }
  }
  if (t == 255) st[NN] = part[256];
}

__global__ __launch_bounds__(256) void k_scatter(const int* ei0, const int* ei1,
                                                 int* cursor, int* srcs) {
  int br = blockIdx.z;
  int e = blockIdx.x * 256 + threadIdx.x;
  if (e >= NE) return;
  const int* ei = br ? ei1 : ei0;
  int t = ei[e], s = ei[NE + e];
  int pos = atomicAdd(cursor + br * NN + t, 1);
  srcs[br * NE + pos] = s;
}

// ---------------- shared phase: PQ strip from lhb (32x128 bf16, stride 136) -------
__device__ __forceinline__ void pq_from_lhb(
    const u16* lhb, const u16* wq, u16* PQ, int m0, int wave, int lane) {
  const int q = lane >> 4, lr = lane & 15;
  f32x4 a3[2][8];
#pragma unroll
  for (int i = 0; i < 2; i++)
#pragma unroll
    for (int j = 0; j < 8; j++) a3[i][j] = (f32x4){0.f, 0.f, 0.f, 0.f};
  bf16x8 bcur[8], bnxt[8];
#pragma unroll
  for (int i = 0; i < 8; i++)
    bcur[i] = *(const bf16x8*)(wq + (size_t)(wave * 128 + i * 16 + lr) * 128 + q * 8);
#pragma unroll
  for (int k0 = 0; k0 < 128; k0 += 32) {
    if (k0 + 32 < 128) {
#pragma unroll
      for (int i = 0; i < 8; i++)
        bnxt[i] = *(const bf16x8*)(wq + (size_t)(wave * 128 + i * 16 + lr) * 128 + k0 + 32 + q * 8);
    }
    bf16x8 af[2];
#pragma unroll
    for (int i = 0; i < 2; i++)
      af[i] = *(const bf16x8*)&lhb[(i * 16 + lr) * 136 + k0 + q * 8];
#pragma unroll
    for (int mi = 0; mi < 2; mi++)
#pragma unroll
      for (int ni = 0; ni < 8; ni++)
        a3[mi][ni] = __builtin_amdgcn_mfma_f32_16x16x32_bf16(af[mi], bcur[ni], a3[mi][ni], 0, 0, 0);
#pragma unroll
    for (int i = 0; i < 8; i++) bcur[i] = bnxt[i];
  }
#pragma unroll
  for (int mi = 0; mi < 2; mi++)
#pragma unroll
    for (int rg = 0; rg < 4; rg++) {
      int grow = m0 + mi * 16 + q * 4 + rg;
      if (grow >= NN) continue;
#pragma unroll
      for (int ni = 0; ni < 8; ni++) {
        int col = wave * 128 + ni * 16 + lr;
        PQ[(size_t)grow * 512 + col] = f2b(a3[mi][ni][rg]);
      }
    }
}

// ---------------- embedding via MFMA: hb = bf16(xb @ W_emb^T + b); + PQ(l=0) ------
__global__ __launch_bounds__(256) void k_embed(
    const u16* xb_all, const u16* wemb, const float* b,
    u16* hb_all, const u16* wpq0, u16* PQ_all) {
  const int br = blockIdx.z;
  const int tid = threadIdx.x;
  const int lane = tid & 63, wave = tid >> 6;
  const int q = lane >> 4, lr = lane & 15;
  const int m0 = blockIdx.x * 32;

  __shared__ alignas(16) u16 lx[32 * 72];
  __shared__ alignas(16) u16 lhb[32 * 136];

  const u16* xb = xb_all + (size_t)br * NN * 64;
  {
    int r = tid >> 3, kc = (tid & 7) * 8;
    int gr = m0 + r;
    u16x8 v = {0, 0, 0, 0, 0, 0, 0, 0};
    if (gr < NN) v = *(const u16x8*)(xb + (size_t)gr * 64 + kc);
    *(u16x8*)&lx[r * 72 + kc] = v;
  }
  __syncthreads();

  const int wn = wave * 32;
  f32x4 acc[2][2];
#pragma unroll
  for (int i = 0; i < 2; i++)
#pragma unroll
    for (int j = 0; j < 2; j++) acc[i][j] = (f32x4){0.f, 0.f, 0.f, 0.f};

#pragma unroll
  for (int k0 = 0; k0 < 64; k0 += 32) {
    bf16x8 af[2], bfr[2];
#pragma unroll
    for (int i = 0; i < 2; i++)
      af[i] = *(const bf16x8*)&lx[(i * 16 + lr) * 72 + k0 + q * 8];
#pragma unroll
    for (int i = 0; i < 2; i++)
      bfr[i] = *(const bf16x8*)(wemb + (size_t)(wn + i * 16 + lr) * 64 + k0 + q * 8);
#pragma unroll
    for (int mi = 0; mi < 2; mi++)
#pragma unroll
      for (int ni = 0; ni < 2; ni++)
        acc[mi][ni] = __builtin_amdgcn_mfma_f32_16x16x32_bf16(af[mi], bfr[ni], acc[mi][ni], 0, 0, 0);
  }

  u16* hbB = hb_all + (size_t)br * NN * HD;
#pragma unroll
  for (int mi = 0; mi < 2; mi++)
#pragma unroll
    for (int rg = 0; rg < 4; rg++) {
      int lrow = mi * 16 + q * 4 + rg;
      int gr = m0 + lrow;
#pragma unroll
      for (int ni = 0; ni < 2; ni++) {
        int col = wn + ni * 16 + lr;
        if (gr < NN) {
          u16 bv = f2b(acc[mi][ni][rg] + b[col]);
          hbB[(size_t)gr * HD + col] = bv;
          lhb[lrow * 136 + col] = bv;
        } else {
          lhb[lrow * 136 + col] = 0;
        }
      }
    }
  __syncthreads();
  pq_from_lhb(lhb, wpq0, PQ_all + (size_t)br * NN * 512, m0, wave, lane);
}

// ---------------- edge phase: S[n] = sum_e relu(P[src_e] + Q[n] + b1) -------------
__global__ __launch_bounds__(256) void k_edge(const u16* PQ, const int* starts,
                                              const int* srcs, const float* b1, u16* S) {
  int br = blockIdx.z;
  int node = blockIdx.x * 4 + (threadIdx.x >> 6);
  int lane = threadIdx.x & 63;
  int half = lane >> 5;
  int c0 = (lane & 31) * 8;
  const u16* PQb = PQ + (size_t)br * NN * 512;
  const int* st = starts + br * (NN + 8);
  const int* sr = srcs + br * NE;
  u16x8 qr = *(const u16x8*)(PQb + (size_t)node * 512 + 256 + c0);
  float qv[8], acc[8];
#pragma unroll
  for (int j = 0; j < 8; j++) { qv[j] = b2f(qr[j]) + b1[c0 + j]; acc[j] = 0.f; }
  int e0 = st[node], e1 = st[node + 1];
  int mid = e0 + ((e1 - e0 + 1) >> 1);
  int e = half ? mid : e0;
  int ee = half ? e1 : mid;
  for (; e + 3 < ee; e += 4) {
    int s0 = sr[e], s1 = sr[e + 1], s2 = sr[e + 2], s3 = sr[e + 3];
    u16x8 p0 = *(const u16x8*)(PQb + (size_t)s0 * 512 + c0);
    u16x8 p1 = *(const u16x8*)(PQb + (size_t)s1 * 512 + c0);
    u16x8 p2 = *(const u16x8*)(PQb + (size_t)s2 * 512 + c0);
    u16x8 p3 = *(const u16x8*)(PQb + (size_t)s3 * 512 + c0);
#pragma unroll
    for (int j = 0; j < 8; j++) {
      float v0 = b2f(p0[j]) + qv[j];
      float v1 = b2f(p1[j]) + qv[j];
      float v2 = b2f(p2[j]) + qv[j];
      float v3 = b2f(p3[j]) + qv[j];
      acc[j] += (v0 > 0.f ? v0 : 0.f) + (v1 > 0.f ? v1 : 0.f)
              + (v2 > 0.f ? v2 : 0.f) + (v3 > 0.f ? v3 : 0.f);
    }
  }
  for (; e + 1 < ee; e += 2) {
    int s0 = sr[e], s1 = sr[e + 1];
    u16x8 p0 = *(const u16x8*)(PQb + (size_t)s0 * 512 + c0);
    u16x8 p1 = *(const u16x8*)(PQb + (size_t)s1 * 512 + c0);
#pragma unroll
    for (int j = 0; j < 8; j++) {
      float v0 = b2f(p0[j]) + qv[j];
      float v1 = b2f(p1[j]) + qv[j];
      acc[j] += (v0 > 0.f ? v0 : 0.f) + (v1 > 0.f ? v1 : 0.f);
    }
  }
  if (e < ee) {
    int s0 = sr[e];
    u16x8 p0 = *(const u16x8*)(PQb + (size_t)s0 * 512 + c0);
#pragma unroll
    for (int j = 0; j < 8; j++) {
      float v0 = b2f(p0[j]) + qv[j];
      acc[j] += (v0 > 0.f ? v0 : 0.f);
    }
  }
#pragma unroll
  for (int j = 0; j < 8; j++) acc[j] += __shfl_xor(acc[j], 32);
  if (half == 0) {
    u16x8 o;
#pragma unroll
    for (int j = 0; j < 8; j++) o[j] = f2b(acc[j]);
    *(u16x8*)(S + (size_t)br * NN * 256 + (size_t)node * 256 + c0) = o;
  }
}

// ---------------- fused update MLP (M-tile 32), bf16 residual state ---------------
// Stage lA = [S-row | hb-row] (K=384). P1: U1 = relu(lA@W1c + b1u + deg*c2), B dbuf
// from global. lU overlays lA. P2: hb = bf16(hb + lU@W2^T + b2). P3: PQ-next/readout.
__global__ __launch_bounds__(256, 4) void k_upd(
    const u16* S_all, u16* hb_all, const u16* w1c, const float* b1u,
    const float* c2l, const int* deg_all, const u16* w2, const float* b2u,
    int mode, const u16* wpq_next, u16* PQ_all,
    const u16* wnode, const float* nb, const int* b0v, const int* b1v, float* g) {
  const int br = blockIdx.z;
  const int tid = threadIdx.x;
  const int lane = tid & 63, wave = tid >> 6;
  const int q = lane >> 4, lr = lane & 15;
  const int m0 = blockIdx.x * 32;

  __shared__ alignas(16) u16 lA[32 * 392];   // [32][384] strip, stride 392
  __shared__ alignas(16) u16 lhb[32 * 136];
  __shared__ int sbat[32];
  u16* lU = lA;  // overlay after phase1 (32*272 <= 32*392)

  const u16* S = S_all + (size_t)br * NN * 256;
  u16* hb = hb_all + (size_t)br * NN * 128;

  // ---- stage A strip: [S | hb] ----
  for (int c = tid; c < 1536; c += 256) {
    int r = c / 48, kc = (c % 48) * 8;
    int gr = m0 + r;
    u16x8 v = {0, 0, 0, 0, 0, 0, 0, 0};
    if (gr < NN) {
      if (kc < 256) v = *(const u16x8*)(S + (size_t)gr * 256 + kc);
      else          v = *(const u16x8*)(hb + (size_t)gr * 128 + (kc - 256));
    }
    *(u16x8*)&lA[r * 392 + kc] = v;
  }
  if (mode == 1 && tid < 32) {
    const int* batch = br ? b1v : b0v;
    int n = m0 + tid;
    sbat[tid] = (n < NN) ? batch[n] : -1;
  }
  __syncthreads();

  // ---- phase 1: af from lA, bfr double-buffered from global w1c ----
  const int wn = wave * 64;
  f32x4 acc[2][4];
#pragma unroll
  for (int i = 0; i < 2; i++)
#pragma unroll
    for (int j = 0; j < 4; j++) acc[i][j] = (f32x4){0.f, 0.f, 0.f, 0.f};

  bf16x8 bcur[4], bnxt[4];
#pragma unroll
  for (int i = 0; i < 4; i++)
    bcur[i] = *(const bf16x8*)(w1c + (size_t)(wn + i * 16 + lr) * 384 + q * 8);
#pragma unroll
  for (int k0 = 0; k0 < 384; k0 += 32) {
    if (k0 + 32 < 384) {
#pragma unroll
      for (int i = 0; i < 4; i++)
        bnxt[i] = *(const bf16x8*)(w1c + (size_t)(wn + i * 16 + lr) * 384 + k0 + 32 + q * 8);
    }
    bf16x8 af[2];
#pragma unroll
    for (int i = 0; i < 2; i++)
      af[i] = *(const bf16x8*)&lA[(i * 16 + lr) * 392 + k0 + q * 8];
#pragma unroll
    for (int mi = 0; mi < 2; mi++)
#pragma unroll
      for (int ni = 0; ni < 4; ni++)
        acc[mi][ni] = __builtin_amdgcn_mfma_f32_16x16x32_bf16(af[mi], bcur[ni], acc[mi][ni], 0, 0, 0);
#pragma unroll
    for (int i = 0; i < 4; i++) bcur[i] = bnxt[i];
  }
  __syncthreads();  // all lA reads done before overlay

  // relu + bias + deg*c2 -> bf16 into lU[32][272]
  const int* deg = deg_all + br * NN;
#pragma unroll
  for (int mi = 0; mi < 2; mi++)
#pragma unroll
    for (int rg = 0; rg < 4; rg++) {
      int row = mi * 16 + q * 4 + rg;
      int gr = m0 + row;
      float d = (gr < NN) ? (float)deg[gr] : 0.f;
#pragma unroll
      for (int ni = 0; ni < 4; ni++) {
        int col = wn + ni * 16 + lr;
        float v = acc[mi][ni][rg] + b1u[col] + d * c2l[col];
        if (v < 0.f) v = 0.f;
        lU[row * 272 + col] = f2b(v);
      }
    }
  __syncthreads();

  // ---- phase 2: af from lU, bfr double-buffered from global w2 ----
  const int wn2 = wave * 32;
  f32x4 acc2[2][2];
#pragma unroll
  for (int i = 0; i < 2; i++)
#pragma unroll
    for (int j = 0; j < 2; j++) acc2[i][j] = (f32x4){0.f, 0.f, 0.f, 0.f};

  bf16x8 b2c[2], b2n[2];
#pragma unroll
  for (int i = 0; i < 2; i++)
    b2c[i] = *(const bf16x8*)(w2 + (size_t)(wn2 + i * 16 + lr) * 256 + q * 8);
#pragma unroll
  for (int k0 = 0; k0 < 256; k0 += 32) {
    if (k0 + 32 < 256) {
#pragma unroll
      for (int i = 0; i < 2; i++)
        b2n[i] = *(const bf16x8*)(w2 + (size_t)(wn2 + i * 16 + lr) * 256 + k0 + 32 + q * 8);
    }
    bf16x8 af[2];
#pragma unroll
    for (int i = 0; i < 2; i++)
      af[i] = *(const bf16x8*)&lU[(i * 16 + lr) * 272 + k0 + q * 8];
#pragma unroll
    for (int mi = 0; mi < 2; mi++)
#pragma unroll
      for (int ni = 0; ni < 2; ni++)
        acc2[mi][ni] = __builtin_amdgcn_mfma_f32_16x16x32_bf16(af[mi], b2c[ni], acc2[mi][ni], 0, 0, 0);
#pragma unroll
    for (int i = 0; i < 2; i++) b2c[i] = b2n[i];
  }

  // residual epilogue in bf16 (+ stage new h into lhb)
#pragma unroll
  for (int mi = 0; mi < 2; mi++)
#pragma unroll
    for (int rg = 0; rg < 4; rg++) {
      int lrow = mi * 16 + q * 4 + rg;
      int grow = m0 + lrow;
#pragma unroll
      for (int ni = 0; ni < 2; ni++) {
        int col = wn2 + ni * 16 + lr;
        if (grow < NN) {
          size_t o = (size_t)grow * 128 + col;
          float nh = b2f(hb[o]) + acc2[mi][ni][rg] + b2u[col];
          u16 bv = f2b(nh);
          hb[o] = bv;
          lhb[lrow * 136 + col] = bv;
        } else {
          lhb[lrow * 136 + col] = 0;
        }
      }
    }
  __syncthreads();

  // ---- phase 3 ----
  if (mode == 0) {
    pq_from_lhb(lhb, wpq_next, PQ_all + (size_t)br * NN * 512, m0, wave, lane);
  } else {
    const int wg = wave * 32;
    f32x4 a3[2][4];  // ni 0-1 gate cols, 2-3 val cols
#pragma unroll
    for (int i = 0; i < 2; i++)
#pragma unroll
      for (int j = 0; j < 4; j++) a3[i][j] = (f32x4){0.f, 0.f, 0.f, 0.f};
#pragma unroll
    for (int k0 = 0; k0 < 128; k0 += 32) {
      bf16x8 af[2], bfr[4];
#pragma unroll
      for (int i = 0; i < 2; i++)
        af[i] = *(const bf16x8*)&lhb[(i * 16 + lr) * 136 + k0 + q * 8];
#pragma unroll
      for (int i = 0; i < 4; i++) {
        int nrow = (i < 2) ? (wg + i * 16 + lr) : (128 + wg + (i - 2) * 16 + lr);
        bfr[i] = *(const bf16x8*)(wnode + (size_t)nrow * 128 + k0 + q * 8);
      }
#pragma unroll
      for (int mi = 0; mi < 2; mi++)
#pragma unroll
        for (int ni = 0; ni < 4; ni++)
          a3[mi][ni] = __builtin_amdgcn_mfma_f32_16x16x32_bf16(af[mi], bfr[ni], a3[mi][ni], 0, 0, 0);
    }
    float* gb = g + (size_t)br * NG * 128;
    float racc[2] = {0.f, 0.f};
    int cur = -1;
#pragma unroll
    for (int mi = 0; mi < 2; mi++)
#pragma unroll
      for (int rg = 0; rg < 4; rg++) {
        int lrow = mi * 16 + q * 4 + rg;
        int bt = sbat[lrow];
        if (bt != cur) {
          if (cur >= 0) {
#pragma unroll
            for (int ni = 0; ni < 2; ni++)
              atomicAdd(gb + (size_t)cur * 128 + wg + ni * 16 + lr, racc[ni]);
          }
          cur = bt;
          racc[0] = 0.f; racc[1] = 0.f;
        }
        if (bt >= 0) {
#pragma unroll
          for (int ni = 0; ni < 2; ni++) {
            int gcol = wg + ni * 16 + lr;
            float gt = a3[mi][ni][rg] + nb[gcol];
            float vl = a3[mi][ni + 2][rg] + nb[128 + gcol];
            racc[ni] += vl / (1.f + __expf(-gt));
          }
        }
      }
    if (cur >= 0) {
#pragma unroll
      for (int ni = 0; ni < 2; ni++)
        atomicAdd(gb + (size_t)cur * 128 + wg + ni * 16 + lr, racc[ni]);
    }
  }
}

// ---------------- final graph GEMM ----------------
__global__ __launch_bounds__(128) void k_final(const float* g, const float* W,
                                               const float* b, float* out) {
  int br = blockIdx.z, gi = blockIdx.x, j = threadIdx.x;
  __shared__ float sg[128];
  sg[j] = g[(size_t)br * NG * 128 + (size_t)gi * 128 + j];
  __syncthreads();
  float acc = b[j];
#pragma unroll
  for (int k = 0; k < 128; k++) acc += sg[k] * W[k * 128 + j];
  out[(size_t)br * NG * 128 + (size_t)gi * 128 + j] = acc;
}

extern "C" void kernel_launch(void* const* d_in, const int* in_sizes, int n_in,
                              void* d_out, int out_size, void* d_ws, size_t ws_size,
                              hipStream_t stream) {
  const float* x1     = (const float*)d_in[0];
  const int*   ei1    = (const int*)d_in[1];
  const int*   bat1   = (const int*)d_in[2];
  const float* x2     = (const float*)d_in[3];
  const int*   ei2    = (const int*)d_in[4];
  const int*   bat2   = (const int*)d_in[5];
  const float* W_emb  = (const float*)d_in[6];
  const float* b_emb  = (const float*)d_in[7];
  const float* msg_W1 = (const float*)d_in[8];
  const float* msg_b1 = (const float*)d_in[9];
  const float* msg_W2 = (const float*)d_in[10];
  const float* msg_b2 = (const float*)d_in[11];
  const float* upd_W1 = (const float*)d_in[12];
  const float* upd_b1 = (const float*)d_in[13];
  const float* upd_W2 = (const float*)d_in[14];
  const float* upd_b2 = (const float*)d_in[15];
  const float* node_W = (const float*)d_in[16];
  const float* node_b = (const float*)d_in[17];
  const float* graph_W = (const float*)d_in[18];
  const float* graph_b = (const float*)d_in[19];
  float* out = (float*)d_out;

  char* ws = (char*)d_ws;
  u16* wt_pq   = (u16*)(ws + WT_PQ);
  u16* wt_u1c  = (u16*)(ws + WT_U1C);
  u16* wt_upd2 = (u16*)(ws + WT_UPD2);
  u16* wt_node = (u16*)(ws + WT_NODE);
  u16* wt_emb  = (u16*)(ws + WT_EMB);
  float* c2    = (float*)(ws + OFF_C2);
  int* deg    = (int*)(ws + OFF_DEG);
  int* starts = (int*)(ws + OFF_ST);
  int* cursor = (int*)(ws + OFF_CUR);
  int* srcs   = (int*)(ws + OFF_SRC);
  u16* hb     = (u16*)(ws + OFF_HB);
  u16* PQ     = (u16*)(ws + OFF_PQ);
  u16* S      = (u16*)(ws + OFF_S);
  float* g    = (float*)(ws + OFF_G);
  u16* xb     = (u16*)(ws + OFF_XB);

  // ---- prep (weights + Wc + c2 + xb + zero deg/g) ----
  k_prep<<<6057, 256, 0, stream>>>(msg_W1, msg_W2, upd_W1, upd_W2, node_W, msg_b2,
                                   W_emb, x1, x2,
                                   wt_pq, wt_u1c, wt_upd2, wt_node, wt_emb, xb,
                                   c2, deg, g);
  k_deg<<<dim3(625, 1, 2), 256, 0, stream>>>(ei1, ei2, deg);
  k_scan<<<dim3(1, 1, 2), 256, 0, stream>>>(deg, starts, cursor);
  k_scatter<<<dim3(625, 1, 2), 256, 0, stream>>>(ei1, ei2, cursor, srcs);
  // embed (MFMA) + PQ(l=0)
  k_embed<<<dim3(313, 1, 2), 256, 0, stream>>>(xb, wt_emb, b_emb, hb, wt_pq, PQ);

  for (int l = 0; l < 2; l++) {
    // S[n] = sum_{e: tgt=n} relu(P[src_e] + Q[n] + b1)
    k_edge<<<dim3(2500, 1, 2), 256, 0, stream>>>(PQ, starts, srcs, msg_b1 + l * 256, S);

    // fused: U1 = relu([S|h]@W1c+..); hb += U1@W2+b2; then PQ(l+1) or readout
    k_upd<<<dim3(313, 1, 2), 256, 0, stream>>>(
        S, hb, wt_u1c + (size_t)l * 98304, upd_b1 + l * 256, c2 + l * 256,
        deg, wt_upd2 + (size_t)l * 32768, upd_b2 + l * 128,
        (l == 0) ? 0 : 1,
        wt_pq + 65536, PQ,
        wt_node, node_b, bat1, bat2, g);
  }

  k_final<<<dim3(NG, 1, 2), 128, 0, stream>>>(g, graph_W, graph_b, out);
}